// Round 9
// baseline (18883.408 us; speedup 1.0000x reference)
//
#include <hip/hip_runtime.h>

// ---- problem constants ----
#define T_SEQ 1000
#define NS 128
#define NE 4
#define DIN 132
#define G3 768
#define WGS 512
#define NWG 64

typedef __attribute__((ext_vector_type(8))) short short8;
typedef __attribute__((ext_vector_type(4))) float floatx4;

// ---- workspace layout (bytes) ----
#define STAMP_OFF 0                // 32 groups * 64B (16 u32 stamps each); A: g<16, B: g>=16
#define HX_OFF    4096
#define HX_BYTES  (32*2*8192)      // per group: 2 slots x 8 frags x 64 lanes x 16B
#define WS_ZERO_BYTES (HX_OFF + HX_BYTES)

#define MFMA16(a,b,c) __builtin_amdgcn_mfma_f32_16x16x32_bf16((a),(b),(c),0,0,0)

__device__ __forceinline__ unsigned short f2bf(float f){
  unsigned u = __float_as_uint(f);
  return (unsigned short)((u + 0x7FFFu + ((u>>16)&1u)) >> 16);   // RNE
}
__device__ __forceinline__ float bf2f(unsigned short b){
  return __uint_as_float(((unsigned)b)<<16);
}
__device__ __forceinline__ unsigned long long ld64a(const void* p){
  return __hip_atomic_load((const unsigned long long*)p, __ATOMIC_RELAXED, __HIP_MEMORY_SCOPE_AGENT);
}
__device__ __forceinline__ unsigned ld32a(const void* p){
  return __hip_atomic_load((const unsigned*)p, __ATOMIC_RELAXED, __HIP_MEMORY_SCOPE_AGENT);
}
__device__ __forceinline__ void st32a(void* p, unsigned v){
  __hip_atomic_store((unsigned*)p, v, __ATOMIC_RELAXED, __HIP_MEMORY_SCOPE_AGENT);
}
__device__ __forceinline__ void flag_st(int* p, int v){
  __hip_atomic_store(p, v, __ATOMIC_RELAXED, __HIP_MEMORY_SCOPE_WORKGROUP);
}
__device__ __forceinline__ int flag_ld(const int* p){
  return __hip_atomic_load(p, __ATOMIC_RELAXED, __HIP_MEMORY_SCOPE_WORKGROUP);
}

__global__ __launch_bounds__(WGS)
void bigru9(
  const float* __restrict__ spike, const float* __restrict__ extin,
  const int* __restrict__ lens,
  const float* __restrict__ WiF, const float* __restrict__ WhF,
  const float* __restrict__ biF, const float* __restrict__ bhF,
  const float* __restrict__ WiB, const float* __restrict__ WhB,
  const float* __restrict__ biB, const float* __restrict__ bhB,
  float* __restrict__ out, char* __restrict__ ws)
{
  const int tid = threadIdx.x;
  const int bid = blockIdx.x;
  const int gA  = bid >> 2;          // fwd group 0..15
  const int gB  = gA + 16;           // bwd group 16..31
  const int s   = bid & 3;           // column-slice 0..3 (64 h-dims each)
  const int b_base = gA << 4;        // 16 examples, shared by both chains
  const int w  = tid >> 6;           // wave 0..7
  const int l  = tid & 63;
  const int dg = w >> 1;             // dim-group 0..3 (16 dims)
  const int ks = w & 1;              // K-half
  const int col = l & 15;
  const int q   = l >> 4;
  const int jd  = s*64 + dg*16 + col;   // global h-dim 0..255

  __shared__ __align__(16) char  ldsXb[4*5*64*16];      // x frags [dir][buf]
  __shared__ __align__(16) char  ldsA[8*64*16];         // staged h frags (shared A/B)
  __shared__ __align__(16) float ldsC[2][4][4][16][20]; // K-split partials per chain
  __shared__ int ldsL[16];
  __shared__ int flagA, flagB;

  unsigned* stgA = (unsigned*)(ws + STAMP_OFF) + gA*16;
  unsigned* stgB = (unsigned*)(ws + STAMP_OFF) + gB*16;
  char*     hxA  = ws + HX_OFF + (size_t)gA*2*8192;
  char*     hxB  = ws + HX_OFF + (size_t)gB*2*8192;

  if (tid < 16) ldsL[tid] = lens[b_base + tid];
  if (tid == 0){ flagA = 0; flagB = 0; }
  for (int i = tid; i < 4*320; i += WGS)
    *(floatx4*)(ldsXb + i*16) = floatx4{0.f,0.f,0.f,0.f};
  __syncthreads();

  // ---- persistent B fragments for BOTH directions (W = W_hi + W_lo) ----
  const int q8 = q*8;
  short8 BhA[4][3][2], BxA[3][3][2];
  short8 BhB[4][3][2], BxB[3][3][2];
  #pragma unroll
  for (int hk=0; hk<4; ++hk){
    const int k0 = (ks*4+hk)*32 + q8;
    #pragma unroll
    for (int gt=0; gt<3; ++gt){
      const int c = gt*256 + jd;
      #pragma unroll
      for (int i=0;i<8;++i){
        float wa = WhF[(size_t)(k0+i)*G3 + c];
        unsigned short ha = f2bf(wa);
        BhA[hk][gt][0][i] = (short)ha;
        BhA[hk][gt][1][i] = (short)f2bf(wa - bf2f(ha));
        float wb = WhB[(size_t)(k0+i)*G3 + c];
        unsigned short hb = f2bf(wb);
        BhB[hk][gt][0][i] = (short)hb;
        BhB[hk][gt][1][i] = (short)f2bf(wb - bf2f(hb));
      }
    }
  }
  #pragma unroll
  for (int xk=0; xk<3; ++xk){
    const bool xv = (ks==0) || (xk<2);
    const int kxg = (ks==0) ? xk : (3+xk);
    const int k0 = kxg*32 + q8;
    #pragma unroll
    for (int gt=0; gt<3; ++gt){
      const int c = gt*256 + jd;
      #pragma unroll
      for (int i=0;i<8;++i){
        float wa = (xv && (k0+i) < DIN) ? WiF[(size_t)(k0+i)*G3 + c] : 0.f;
        unsigned short ha = f2bf(wa);
        BxA[xk][gt][0][i] = (short)ha;
        BxA[xk][gt][1][i] = (short)f2bf(wa - bf2f(ha));
        float wb = (xv && (k0+i) < DIN) ? WiB[(size_t)(k0+i)*G3 + c] : 0.f;
        unsigned short hb = f2bf(wb);
        BxB[xk][gt][0][i] = (short)hb;
        BxB[xk][gt][1][i] = (short)f2bf(wb - bf2f(hb));
      }
    }
  }

  const float birA = biF[jd], bizA = biF[256+jd], binA = biF[512+jd], bhvA = bhF[jd];
  const float birB = biB[jd], bizB = biB[256+jd], binB = biB[512+jd], bhvB = bhB[jd];
  int   Lr[4];
  float holdA[4], holdB[4];
  #pragma unroll
  for (int j=0;j<4;++j){ Lr[j] = ldsL[q*4+j]; holdA[j] = 0.f; holdB[j] = 0.f; }

  // x staging: pack m (row = m/33, k0 = (m%33)*4); dirf: 0 fwd, 1 bwd
  auto xloadD = [&](int m, int tt, int dirf)->float4{
    const int row = m/33, pk = m - row*33, k0 = pk*4;
    const int L = ldsL[row];
    int tp = dirf ? (L-1-tt) : tt;
    if (tp < 0) tp += T_SEQ;
    const size_t xb = (size_t)(b_base+row)*T_SEQ + tp;
    if (k0 < NS) return *(const float4*)(spike + xb*NS + k0);
    return *(const float4*)(extin + xb*NE);
  };
  auto xstoreD = [&](int m, float4 v, int buf, int dirf){
    const int row = m/33, pk = m - row*33, k0 = pk*4;
    const int kg = k0>>5, sub = (k0>>3)&3, ii = k0&7;
    const int off = dirf*10240 + buf*5120 + ((kg*64 + row + 16*sub)*8 + ii)*2;
    unsigned lo = (unsigned)f2bf(v.x) | (((unsigned)f2bf(v.y))<<16);
    unsigned hi = (unsigned)f2bf(v.z) | (((unsigned)f2bf(v.w))<<16);
    *(unsigned*)(ldsXb + off)     = lo;
    *(unsigned*)(ldsXb + off + 4) = hi;
  };

  // prologue: stage x(0) for both chains into buffer 0
  {
    float4 a = xloadD(tid, 0, 0);  xstoreD(tid, a, 0, 0);
    float4 b = xloadD(tid, 0, 1);  xstoreD(tid, b, 0, 1);
    if (tid < 16){
      float4 a2 = xloadD(tid+512, 0, 0); xstoreD(tid+512, a2, 0, 0);
      float4 b2 = xloadD(tid+512, 0, 1); xstoreD(tid+512, b2, 0, 1);
    }
  }
  __syncthreads();

  const int r0 = dg*64 + l;                 // ks0 staging pack base
  const int kg_o = jd >> 5, d5 = jd & 31;   // export addressing
  const int wslot = s*4 + dg;               // producer stamp slot (ks1 waves)

  for (int t=0; t<T_SEQ; ++t){
    const int cur = t & 1, nxt = cur ^ 1;

    // issue x(t+1) loads for both chains (ks0 threads)
    float4 sa0, sa1, sa2, sb0, sb1, sb2;
    if (ks==0 && t < T_SEQ-1){
      sa0 = xloadD(r0, t+1, 0);      sb0 = xloadD(r0, t+1, 1);
      sa1 = xloadD(r0+256, t+1, 0);  sb1 = xloadD(r0+256, t+1, 1);
      if (r0 < 16){ sa2 = xloadD(r0+512, t+1, 0); sb2 = xloadD(r0+512, t+1, 1); }
    }

    // ================= chain A (fwd) =================
    floatx4 aR={0.f,0.f,0.f,0.f}, aZ={0.f,0.f,0.f,0.f}, aNH={0.f,0.f,0.f,0.f}, aNX={0.f,0.f,0.f,0.f};
    if (ks==0){
      #pragma unroll
      for (int xk=0; xk<3; ++xk){
        const short8 a = *(const short8*)(ldsXb + (cur*320 + xk*64 + l)*16);
        aR  = MFMA16(a, BxA[xk][0][0], aR ); aZ  = MFMA16(a, BxA[xk][1][0], aZ ); aNX = MFMA16(a, BxA[xk][2][0], aNX);
        aR  = MFMA16(a, BxA[xk][0][1], aR ); aZ  = MFMA16(a, BxA[xk][1][1], aZ ); aNX = MFMA16(a, BxA[xk][2][1], aNX);
      }
    } else {
      #pragma unroll
      for (int xk=0; xk<2; ++xk){
        const short8 a = *(const short8*)(ldsXb + (cur*320 + (3+xk)*64 + l)*16);
        aR  = MFMA16(a, BxA[xk][0][0], aR ); aZ  = MFMA16(a, BxA[xk][1][0], aZ ); aNX = MFMA16(a, BxA[xk][2][0], aNX);
        aR  = MFMA16(a, BxA[xk][0][1], aR ); aZ  = MFMA16(a, BxA[xk][1][1], aZ ); aNX = MFMA16(a, BxA[xk][2][1], aNX);
      }
    }

    // poll A (wave0 only) -> LDS flag; everyone spins on LDS
    if (t > 0){
      if (w == 0){
        const unsigned* sp = stgA + (l & 15);
        while (true){
          unsigned v = ld32a(sp);
          if (__ballot(v >= (unsigned)t) == ~0ull) break;
          __builtin_amdgcn_s_sleep(1);
        }
        if (l == 0) flag_st(&flagA, t);
      }
      while (flag_ld(&flagA) < t) __builtin_amdgcn_s_sleep(1);
      asm volatile("" ::: "memory");
    }
    // cooperative stage of A's h frags: 512 threads x 16B = 8KB, no redundancy
    {
      const char* p = hxA + nxt*8192 + tid*16;
      union { unsigned long long qq[2]; short8 v; } u;
      u.qq[0] = ld64a(p); u.qq[1] = ld64a(p+8);
      *(short8*)(ldsA + tid*16) = u.v;
    }
    __syncthreads();   // S1: ldsA ready

    #pragma unroll
    for (int hk=0; hk<4; ++hk){
      const short8 a = *(const short8*)(ldsA + (((ks*4+hk)*64) + l)*16);
      aR  = MFMA16(a, BhA[hk][0][0], aR ); aZ  = MFMA16(a, BhA[hk][1][0], aZ ); aNH = MFMA16(a, BhA[hk][2][0], aNH);
      aR  = MFMA16(a, BhA[hk][0][1], aR ); aZ  = MFMA16(a, BhA[hk][1][1], aZ ); aNH = MFMA16(a, BhA[hk][2][1], aNH);
    }
    if (ks==0){
      *(floatx4*)&ldsC[0][dg][0][col][q*4] = aR;
      *(floatx4*)&ldsC[0][dg][1][col][q*4] = aZ;
      *(floatx4*)&ldsC[0][dg][2][col][q*4] = aNH;
      *(floatx4*)&ldsC[0][dg][3][col][q*4] = aNX;
    }
    // wave2 polls chain B's stamps while others head to bar1
    if (w == 2 && t > 0){
      const unsigned* sp = stgB + (l & 15);
      while (true){
        unsigned v = ld32a(sp);
        if (__ballot(v >= (unsigned)t) == ~0ull) break;
        __builtin_amdgcn_s_sleep(1);
      }
      if (l == 0) flag_st(&flagB, t);
    }
    __syncthreads();   // bar1: ldsC[0] ready; ldsA free for reuse

    float hnvA[4];
    unsigned dwjA[4];
    if (ks==1){
      aR  += *(const floatx4*)&ldsC[0][dg][0][col][q*4];
      aZ  += *(const floatx4*)&ldsC[0][dg][1][col][q*4];
      aNH += *(const floatx4*)&ldsC[0][dg][2][col][q*4];
      aNX += *(const floatx4*)&ldsC[0][dg][3][col][q*4];
      #pragma unroll
      for (int j=0;j<4;++j){
        const float gr = aR[j] + birA;
        const float gz = aZ[j] + bizA;
        const float r = __fdividef(1.f, 1.f + __expf(-gr));
        const float z = __fdividef(1.f, 1.f + __expf(-gz));
        float pn = aNX[j] + binA + r*(aNH[j] + bhvA);
        pn = fminf(fmaxf(pn, -20.f), 20.f);
        const float e2 = __expf(-2.f*pn);
        const float n  = __fdividef(1.f - e2, 1.f + e2);
        const float hn  = (1.f - z)*n + z*holdA[j];
        const float hnx = (t < Lr[j]) ? hn : holdA[j];
        holdA[j] = hnx;
        hnvA[j] = hn;
        unsigned bf = f2bf(hnx);
        unsigned ot = (unsigned)__shfl_xor((int)bf, 1);
        dwjA[j] = (l & 1) ? 0u : (bf | (ot << 16));
      }
      if (t < T_SEQ-1 && (l & 1) == 0){
        char* dst = hxA + cur*8192 + ((kg_o*64 + 16*(d5>>3))*16 + (d5&7)*2);
        #pragma unroll
        for (int j=0;j<4;++j)
          st32a(dst + (q*4+j)*16, dwjA[j]);
      }
    } else if (t < T_SEQ-1){
      xstoreD(r0, sa0, nxt, 0);
      xstoreD(r0+256, sa1, nxt, 0);
      if (r0 < 16) xstoreD(r0+512, sa2, nxt, 0);
    }

    // ================= chain B (bwd) =================
    floatx4 bR={0.f,0.f,0.f,0.f}, bZ={0.f,0.f,0.f,0.f}, bNH={0.f,0.f,0.f,0.f}, bNX={0.f,0.f,0.f,0.f};
    if (ks==0){
      #pragma unroll
      for (int xk=0; xk<3; ++xk){
        const short8 a = *(const short8*)(ldsXb + ((640 + cur*320) + xk*64 + l)*16);
        bR  = MFMA16(a, BxB[xk][0][0], bR ); bZ  = MFMA16(a, BxB[xk][1][0], bZ ); bNX = MFMA16(a, BxB[xk][2][0], bNX);
        bR  = MFMA16(a, BxB[xk][0][1], bR ); bZ  = MFMA16(a, BxB[xk][1][1], bZ ); bNX = MFMA16(a, BxB[xk][2][1], bNX);
      }
    } else {
      #pragma unroll
      for (int xk=0; xk<2; ++xk){
        const short8 a = *(const short8*)(ldsXb + ((640 + cur*320) + (3+xk)*64 + l)*16);
        bR  = MFMA16(a, BxB[xk][0][0], bR ); bZ  = MFMA16(a, BxB[xk][1][0], bZ ); bNX = MFMA16(a, BxB[xk][2][0], bNX);
        bR  = MFMA16(a, BxB[xk][0][1], bR ); bZ  = MFMA16(a, BxB[xk][1][1], bZ ); bNX = MFMA16(a, BxB[xk][2][1], bNX);
      }
    }
    // chain A stamp: drain exports (overlapped with the B x-MFMAs above), then release
    if (ks==1 && t < T_SEQ-1){
      asm volatile("s_waitcnt vmcnt(0)" ::: "memory");
      __builtin_amdgcn_sched_barrier(0);
      if (l == 0) st32a(stgA + wslot, (unsigned)(t+1));
    }

    if (t > 0){
      while (flag_ld(&flagB) < t) __builtin_amdgcn_s_sleep(1);
      asm volatile("" ::: "memory");
    }
    // cooperative stage of B's h frags (reuses ldsA; all readers passed bar1)
    {
      const char* p = hxB + nxt*8192 + tid*16;
      union { unsigned long long qq[2]; short8 v; } u;
      u.qq[0] = ld64a(p); u.qq[1] = ld64a(p+8);
      *(short8*)(ldsA + tid*16) = u.v;
    }
    __syncthreads();   // S2: ldsA ready (B)

    #pragma unroll
    for (int hk=0; hk<4; ++hk){
      const short8 a = *(const short8*)(ldsA + (((ks*4+hk)*64) + l)*16);
      bR  = MFMA16(a, BhB[hk][0][0], bR ); bZ  = MFMA16(a, BhB[hk][1][0], bZ ); bNH = MFMA16(a, BhB[hk][2][0], bNH);
      bR  = MFMA16(a, BhB[hk][0][1], bR ); bZ  = MFMA16(a, BhB[hk][1][1], bZ ); bNH = MFMA16(a, BhB[hk][2][1], bNH);
    }
    if (ks==0){
      *(floatx4*)&ldsC[1][dg][0][col][q*4] = bR;
      *(floatx4*)&ldsC[1][dg][1][col][q*4] = bZ;
      *(floatx4*)&ldsC[1][dg][2][col][q*4] = bNH;
      *(floatx4*)&ldsC[1][dg][3][col][q*4] = bNX;
    }
    __syncthreads();   // bar2: ldsC[1] ready

    if (ks==1){
      bR  += *(const floatx4*)&ldsC[1][dg][0][col][q*4];
      bZ  += *(const floatx4*)&ldsC[1][dg][1][col][q*4];
      bNH += *(const floatx4*)&ldsC[1][dg][2][col][q*4];
      bNX += *(const floatx4*)&ldsC[1][dg][3][col][q*4];
      float hnvB[4];
      unsigned dwjB[4];
      #pragma unroll
      for (int j=0;j<4;++j){
        const float gr = bR[j] + birB;
        const float gz = bZ[j] + bizB;
        const float r = __fdividef(1.f, 1.f + __expf(-gr));
        const float z = __fdividef(1.f, 1.f + __expf(-gz));
        float pn = bNX[j] + binB + r*(bNH[j] + bhvB);
        pn = fminf(fmaxf(pn, -20.f), 20.f);
        const float e2 = __expf(-2.f*pn);
        const float n  = __fdividef(1.f - e2, 1.f + e2);
        const float hn  = (1.f - z)*n + z*holdB[j];
        const float hnx = (t < Lr[j]) ? hn : holdB[j];
        holdB[j] = hnx;
        hnvB[j] = hn;
        unsigned bf = f2bf(hnx);
        unsigned ot = (unsigned)__shfl_xor((int)bf, 1);
        dwjB[j] = (l & 1) ? 0u : (bf | (ot << 16));
      }
      if (t < T_SEQ-1 && (l & 1) == 0){
        char* dst = hxB + cur*8192 + ((kg_o*64 + 16*(d5>>3))*16 + (d5&7)*2);
        #pragma unroll
        for (int j=0;j<4;++j)
          st32a(dst + (q*4+j)*16, dwjB[j]);
      }
      // out stores for BOTH chains (L2 write-back absorbs; covered by the drain)
      #pragma unroll
      for (int j=0;j<4;++j){
        const int rj = q*4 + j;
        out[((size_t)(b_base+rj)*T_SEQ + t)*512 + jd] = hnvA[j];
        int tp = Lr[j]-1-t;
        if (tp < 0) tp += T_SEQ;
        out[((size_t)(b_base+rj)*T_SEQ + tp)*512 + 256 + jd] = hnvB[j];
      }
      if (t < T_SEQ-1){
        asm volatile("s_waitcnt vmcnt(0)" ::: "memory");
        __builtin_amdgcn_sched_barrier(0);
        if (l == 0) st32a(stgB + wslot, (unsigned)(t+1));
      }
    } else if (t < T_SEQ-1){
      xstoreD(r0, sb0, nxt, 1);
      xstoreD(r0+256, sb1, nxt, 1);
      if (r0 < 16) xstoreD(r0+512, sb2, nxt, 1);
    }
    __syncthreads();   // bar3
  }
}

extern "C" void kernel_launch(void* const* d_in, const int* in_sizes, int n_in,
                              void* d_out, int out_size, void* d_ws, size_t ws_size,
                              hipStream_t stream) {
  (void)in_sizes; (void)n_in; (void)out_size; (void)ws_size;
  const float* spike = (const float*)d_in[0];
  const float* extin = (const float*)d_in[1];
  const int*   lens  = (const int*)  d_in[2];
  const float* WiF   = (const float*)d_in[3];
  const float* WhF   = (const float*)d_in[4];
  const float* biF   = (const float*)d_in[5];
  const float* bhF   = (const float*)d_in[6];
  const float* WiB   = (const float*)d_in[7];
  const float* WhB   = (const float*)d_in[8];
  const float* biB   = (const float*)d_in[9];
  const float* bhB   = (const float*)d_in[10];
  float* out = (float*)d_out;
  char* ws = (char*)d_ws;

  // zero stamps + both hx slots of all groups (slot 1 must read h=0 at t=0;
  // also resets state between graph replays)
  hipMemsetAsync(ws, 0, WS_ZERO_BYTES, stream);
  bigru9<<<dim3(NWG), dim3(WGS), 0, stream>>>(
      spike, extin, lens, WiF, WhF, biF, bhF, WiB, WhB, biB, bhB, out, ws);
}

// Round 10
// 8066.080 us; speedup vs baseline: 2.3411x; 2.3411x over previous
//
#include <hip/hip_runtime.h>

// ---- problem constants ----
#define T_SEQ 1000
#define NS 128
#define NE 4
#define DIN 132
#define G3 768
#define WGS 512
#define NWG 64

typedef __attribute__((ext_vector_type(8))) short short8;
typedef __attribute__((ext_vector_type(4))) float floatx4;

// ---- workspace layout (bytes) ----
#define STAMP_OFF 0                // 32 groups * 64B (16 u32 stamps each)
#define HX_OFF    4096
#define HX_BYTES  (32*2*8192)      // per group: 2 slots x 8 frags x 64 lanes x 16B
#define WS_ZERO_BYTES (HX_OFF + HX_BYTES)

#define MFMA16(a,b,c) __builtin_amdgcn_mfma_f32_16x16x32_bf16((a),(b),(c),0,0,0)

__device__ __forceinline__ unsigned short f2bf(float f){
  unsigned u = __float_as_uint(f);
  return (unsigned short)((u + 0x7FFFu + ((u>>16)&1u)) >> 16);   // RNE
}
__device__ __forceinline__ float bf2f(unsigned short b){
  return __uint_as_float(((unsigned)b)<<16);
}
__device__ __forceinline__ unsigned long long ld64a(const void* p){
  return __hip_atomic_load((const unsigned long long*)p, __ATOMIC_RELAXED, __HIP_MEMORY_SCOPE_AGENT);
}
__device__ __forceinline__ unsigned ld32a(const void* p){
  return __hip_atomic_load((const unsigned*)p, __ATOMIC_RELAXED, __HIP_MEMORY_SCOPE_AGENT);
}
__device__ __forceinline__ void st32a(void* p, unsigned v){
  __hip_atomic_store((unsigned*)p, v, __ATOMIC_RELAXED, __HIP_MEMORY_SCOPE_AGENT);
}

__global__ __launch_bounds__(WGS)
void bigru10(
  const float* __restrict__ spike, const float* __restrict__ extin,
  const int* __restrict__ lens,
  const float* __restrict__ WiF, const float* __restrict__ WhF,
  const float* __restrict__ biF, const float* __restrict__ bhF,
  const float* __restrict__ WiB, const float* __restrict__ WhB,
  const float* __restrict__ biB, const float* __restrict__ bhB,
  float* __restrict__ out, char* __restrict__ ws)
{
  const int tid = threadIdx.x;
  const int bid = blockIdx.x;
  const int p  = (bid >> 2) & 7;     // pair index 0..7
  const int d  = bid >> 5;           // direction 0 fwd / 1 bwd
  const int s  = bid & 3;            // column-slice 0..3 (64 h-dims each)
  const int gA = d*16 + p;           // chain A group
  const int gB = gA + 8;             // chain B group (same dir -> same weights)
  const int b_baseA = p << 4;
  const int b_baseB = (p + 8) << 4;
  const int w  = tid >> 6;           // wave 0..7
  const int l  = tid & 63;
  const int dg = w >> 1;             // dim-group 0..3 (16 dims)
  const int ks = w & 1;              // K-half
  const int col = l & 15;
  const int q   = l >> 4;
  const int jd  = s*64 + dg*16 + col;   // global h-dim 0..255

  const float* Wi  = d ? WiB : WiF;
  const float* Wh  = d ? WhB : WhF;
  const float* bi  = d ? biB : biF;
  const float* bhn = d ? bhB : bhF;

  __shared__ __align__(16) char  ldsXb[2*2*5*64*16];    // [grp][buf] x A-frags
  __shared__ __align__(16) float ldsC[2][4][4][16][20]; // [grp] K-split partials
  __shared__ int ldsL[32];

  unsigned* stgA = (unsigned*)(ws + STAMP_OFF) + gA*16;
  unsigned* stgB = (unsigned*)(ws + STAMP_OFF) + gB*16;
  char*     hxA  = ws + HX_OFF + (size_t)gA*2*8192;
  char*     hxB  = ws + HX_OFF + (size_t)gB*2*8192;

  if (tid < 16)      ldsL[tid]    = lens[b_baseA + tid];
  else if (tid < 32) ldsL[tid]    = lens[b_baseB + tid - 16];
  for (int i = tid; i < 2*2*320; i += WGS)
    *(floatx4*)(ldsXb + i*16) = floatx4{0.f,0.f,0.f,0.f};
  __syncthreads();

  // ---- persistent B fragments, ONE direction (W = W_hi + W_lo, both bf16) ----
  const int q8 = q*8;
  short8 Bh[4][3][2];   // [h-kg][gate][hi/lo]
  short8 Bx[3][3][2];   // [x-kg][gate][hi/lo]
  #pragma unroll
  for (int hk=0; hk<4; ++hk){
    const int k0 = (ks*4+hk)*32 + q8;
    #pragma unroll
    for (int gt=0; gt<3; ++gt){
      const int c = gt*256 + jd;
      #pragma unroll
      for (int i=0;i<8;++i){
        float wv = Wh[(size_t)(k0+i)*G3 + c];
        unsigned short hb = f2bf(wv);
        Bh[hk][gt][0][i] = (short)hb;
        Bh[hk][gt][1][i] = (short)f2bf(wv - bf2f(hb));
      }
    }
  }
  #pragma unroll
  for (int xk=0; xk<3; ++xk){
    const bool xv = (ks==0) || (xk<2);
    const int kxg = (ks==0) ? xk : (3+xk);
    const int k0 = kxg*32 + q8;
    #pragma unroll
    for (int gt=0; gt<3; ++gt){
      const int c = gt*256 + jd;
      #pragma unroll
      for (int i=0;i<8;++i){
        float wv = (xv && (k0+i) < DIN) ? Wi[(size_t)(k0+i)*G3 + c] : 0.f;
        unsigned short hb = f2bf(wv);
        Bx[xk][gt][0][i] = (short)hb;
        Bx[xk][gt][1][i] = (short)f2bf(wv - bf2f(hb));
      }
    }
  }

  const float bir = bi[jd], biz = bi[256+jd], bin = bi[512+jd], bhv = bhn[jd];
  int   LrA[4], LrB[4];
  float holdA[4], holdB[4];
  #pragma unroll
  for (int j=0;j<4;++j){
    LrA[j] = ldsL[q*4+j]; LrB[j] = ldsL[16+q*4+j];
    holdA[j] = 0.f; holdB[j] = 0.f;
  }

  // x staging: pack m (row = m/33, k0 = (m%33)*4); grp 0=A, 1=B
  auto xloadG = [&](int m, int tt, int grp)->float4{
    const int row = m/33, pk = m - row*33, k0 = pk*4;
    const int L = ldsL[grp*16 + row];
    int tp = d ? (L-1-tt) : tt;
    if (tp < 0) tp += T_SEQ;
    const int bb = grp ? b_baseB : b_baseA;
    const size_t xb = (size_t)(bb+row)*T_SEQ + tp;
    if (k0 < NS) return *(const float4*)(spike + xb*NS + k0);
    return *(const float4*)(extin + xb*NE);
  };
  auto xstoreG = [&](int m, float4 v, int buf, int grp){
    const int row = m/33, pk = m - row*33, k0 = pk*4;
    const int kg = k0>>5, sub = (k0>>3)&3, ii = k0&7;
    const int off = grp*10240 + buf*5120 + ((kg*64 + row + 16*sub)*8 + ii)*2;
    unsigned lo = (unsigned)f2bf(v.x) | (((unsigned)f2bf(v.y))<<16);
    unsigned hi = (unsigned)f2bf(v.z) | (((unsigned)f2bf(v.w))<<16);
    *(unsigned*)(ldsXb + off)     = lo;
    *(unsigned*)(ldsXb + off + 4) = hi;
  };

  // prologue: stage x(0) for both chains into buffer 0
  {
    float4 a = xloadG(tid, 0, 0);  xstoreG(tid, a, 0, 0);
    float4 b = xloadG(tid, 0, 1);  xstoreG(tid, b, 0, 1);
    if (tid < 16){
      float4 a2 = xloadG(tid+512, 0, 0); xstoreG(tid+512, a2, 0, 0);
      float4 b2 = xloadG(tid+512, 0, 1); xstoreG(tid+512, b2, 0, 1);
    }
  }
  __syncthreads();

  const int r0 = dg*64 + l;                 // ks0 staging pack base
  const int kg_o = jd >> 5, d5 = jd & 31;   // export addressing
  const int wslot = s*4 + dg;               // producer stamp slot (ks1 waves)

  for (int t=0; t<T_SEQ; ++t){
    const int cur = t & 1, nxt = cur ^ 1;

    // ================= chain A =================
    float4 sa0, sa1, sa2;
    if (ks==0 && t < T_SEQ-1){
      sa0 = xloadG(r0, t+1, 0);
      sa1 = xloadG(r0+256, t+1, 0);
      if (r0 < 16) sa2 = xloadG(r0+512, t+1, 0);
    }

    floatx4 aR={0.f,0.f,0.f,0.f}, aZ={0.f,0.f,0.f,0.f}, aNH={0.f,0.f,0.f,0.f}, aNX={0.f,0.f,0.f,0.f};
    if (ks==0){
      #pragma unroll
      for (int xk=0; xk<3; ++xk){
        const short8 a = *(const short8*)(ldsXb + ((cur*320) + xk*64 + l)*16);
        aR  = MFMA16(a, Bx[xk][0][0], aR ); aZ  = MFMA16(a, Bx[xk][1][0], aZ ); aNX = MFMA16(a, Bx[xk][2][0], aNX);
        aR  = MFMA16(a, Bx[xk][0][1], aR ); aZ  = MFMA16(a, Bx[xk][1][1], aZ ); aNX = MFMA16(a, Bx[xk][2][1], aNX);
      }
    } else {
      #pragma unroll
      for (int xk=0; xk<2; ++xk){
        const short8 a = *(const short8*)(ldsXb + ((cur*320) + (3+xk)*64 + l)*16);
        aR  = MFMA16(a, Bx[xk][0][0], aR ); aZ  = MFMA16(a, Bx[xk][1][0], aZ ); aNX = MFMA16(a, Bx[xk][2][0], aNX);
        aR  = MFMA16(a, Bx[xk][0][1], aR ); aZ  = MFMA16(a, Bx[xk][1][1], aZ ); aNX = MFMA16(a, Bx[xk][2][1], aNX);
      }
    }

    if (t > 0){
      const unsigned* sp = stgA + (l & 15);
      while (true){
        unsigned v = ld32a(sp);
        if (__ballot(v >= (unsigned)t) == ~0ull) break;
        __builtin_amdgcn_s_sleep(1);
      }
      asm volatile("" ::: "memory");
    }

    short8 hfA[4];
    {
      const char* hsrc = hxA + nxt*8192;
      #pragma unroll
      for (int hk=0; hk<4; ++hk){
        const char* pp = hsrc + (((ks*4+hk)*64 + l)*16);
        union { unsigned long long qq[2]; short8 v; } u;
        u.qq[0] = ld64a(pp); u.qq[1] = ld64a(pp+8);
        hfA[hk] = u.v;
      }
    }

    #pragma unroll
    for (int hk=0; hk<4; ++hk){
      aR  = MFMA16(hfA[hk], Bh[hk][0][0], aR ); aZ  = MFMA16(hfA[hk], Bh[hk][1][0], aZ ); aNH = MFMA16(hfA[hk], Bh[hk][2][0], aNH);
      aR  = MFMA16(hfA[hk], Bh[hk][0][1], aR ); aZ  = MFMA16(hfA[hk], Bh[hk][1][1], aZ ); aNH = MFMA16(hfA[hk], Bh[hk][2][1], aNH);
    }

    if (ks==0){
      *(floatx4*)&ldsC[0][dg][0][col][q*4] = aR;
      *(floatx4*)&ldsC[0][dg][1][col][q*4] = aZ;
      *(floatx4*)&ldsC[0][dg][2][col][q*4] = aNH;
      *(floatx4*)&ldsC[0][dg][3][col][q*4] = aNX;
    }
    __syncthreads();   // bar1

    if (ks==1){
      aR  += *(const floatx4*)&ldsC[0][dg][0][col][q*4];
      aZ  += *(const floatx4*)&ldsC[0][dg][1][col][q*4];
      aNH += *(const floatx4*)&ldsC[0][dg][2][col][q*4];
      aNX += *(const floatx4*)&ldsC[0][dg][3][col][q*4];
      unsigned dwj[4];
      float hnv[4];
      #pragma unroll
      for (int j=0;j<4;++j){
        const float gr = aR[j] + bir;
        const float gz = aZ[j] + biz;
        const float r = __fdividef(1.f, 1.f + __expf(-gr));
        const float z = __fdividef(1.f, 1.f + __expf(-gz));
        float pn = aNX[j] + bin + r*(aNH[j] + bhv);
        pn = fminf(fmaxf(pn, -20.f), 20.f);
        const float e2 = __expf(-2.f*pn);
        const float n  = __fdividef(1.f - e2, 1.f + e2);
        const float hn  = (1.f - z)*n + z*holdA[j];
        const float hnx = (t < LrA[j]) ? hn : holdA[j];
        holdA[j] = hnx;
        hnv[j] = hn;
        unsigned bf = f2bf(hnx);
        unsigned ot = (unsigned)__shfl_xor((int)bf, 1);
        dwj[j] = (l & 1) ? 0u : (bf | (ot << 16));
      }
      if (t < T_SEQ-1){
        if ((l & 1) == 0){
          char* dst = hxA + cur*8192 + ((kg_o*64 + 16*(d5>>3))*16 + (d5&7)*2);
          #pragma unroll
          for (int j=0;j<4;++j)
            st32a(dst + (q*4+j)*16, dwj[j]);
        }
        asm volatile("s_waitcnt vmcnt(0)" ::: "memory");
        __builtin_amdgcn_sched_barrier(0);
        if (l == 0)
          st32a(stgA + wslot, (unsigned)(t+1));
      }
      #pragma unroll
      for (int j=0;j<4;++j){
        const int rj = q*4 + j;
        int tp = d ? (LrA[j]-1-t) : t;
        if (tp < 0) tp += T_SEQ;
        out[((size_t)(b_baseA+rj)*T_SEQ + tp)*512 + d*256 + jd] = hnv[j];
      }
    } else {
      if (t < T_SEQ-1){
        xstoreG(r0, sa0, nxt, 0);
        xstoreG(r0+256, sa1, nxt, 0);
        if (r0 < 16) xstoreG(r0+512, sa2, nxt, 0);
      }
    }

    // ================= chain B =================
    float4 sb0, sb1, sb2;
    if (ks==0 && t < T_SEQ-1){
      sb0 = xloadG(r0, t+1, 1);
      sb1 = xloadG(r0+256, t+1, 1);
      if (r0 < 16) sb2 = xloadG(r0+512, t+1, 1);
    }

    floatx4 bR={0.f,0.f,0.f,0.f}, bZ={0.f,0.f,0.f,0.f}, bNH={0.f,0.f,0.f,0.f}, bNX={0.f,0.f,0.f,0.f};
    if (ks==0){
      #pragma unroll
      for (int xk=0; xk<3; ++xk){
        const short8 a = *(const short8*)(ldsXb + ((640 + cur*320) + xk*64 + l)*16);
        bR  = MFMA16(a, Bx[xk][0][0], bR ); bZ  = MFMA16(a, Bx[xk][1][0], bZ ); bNX = MFMA16(a, Bx[xk][2][0], bNX);
        bR  = MFMA16(a, Bx[xk][0][1], bR ); bZ  = MFMA16(a, Bx[xk][1][1], bZ ); bNX = MFMA16(a, Bx[xk][2][1], bNX);
      }
    } else {
      #pragma unroll
      for (int xk=0; xk<2; ++xk){
        const short8 a = *(const short8*)(ldsXb + ((640 + cur*320) + (3+xk)*64 + l)*16);
        bR  = MFMA16(a, Bx[xk][0][0], bR ); bZ  = MFMA16(a, Bx[xk][1][0], bZ ); bNX = MFMA16(a, Bx[xk][2][0], bNX);
        bR  = MFMA16(a, Bx[xk][0][1], bR ); bZ  = MFMA16(a, Bx[xk][1][1], bZ ); bNX = MFMA16(a, Bx[xk][2][1], bNX);
      }
    }

    if (t > 0){
      const unsigned* sp = stgB + (l & 15);
      while (true){
        unsigned v = ld32a(sp);
        if (__ballot(v >= (unsigned)t) == ~0ull) break;
        __builtin_amdgcn_s_sleep(1);
      }
      asm volatile("" ::: "memory");
    }

    short8 hfB[4];
    {
      const char* hsrc = hxB + nxt*8192;
      #pragma unroll
      for (int hk=0; hk<4; ++hk){
        const char* pp = hsrc + (((ks*4+hk)*64 + l)*16);
        union { unsigned long long qq[2]; short8 v; } u;
        u.qq[0] = ld64a(pp); u.qq[1] = ld64a(pp+8);
        hfB[hk] = u.v;
      }
    }

    #pragma unroll
    for (int hk=0; hk<4; ++hk){
      bR  = MFMA16(hfB[hk], Bh[hk][0][0], bR ); bZ  = MFMA16(hfB[hk], Bh[hk][1][0], bZ ); bNH = MFMA16(hfB[hk], Bh[hk][2][0], bNH);
      bR  = MFMA16(hfB[hk], Bh[hk][0][1], bR ); bZ  = MFMA16(hfB[hk], Bh[hk][1][1], bZ ); bNH = MFMA16(hfB[hk], Bh[hk][2][1], bNH);
    }

    if (ks==0){
      *(floatx4*)&ldsC[1][dg][0][col][q*4] = bR;
      *(floatx4*)&ldsC[1][dg][1][col][q*4] = bZ;
      *(floatx4*)&ldsC[1][dg][2][col][q*4] = bNH;
      *(floatx4*)&ldsC[1][dg][3][col][q*4] = bNX;
    }
    __syncthreads();   // bar2

    if (ks==1){
      bR  += *(const floatx4*)&ldsC[1][dg][0][col][q*4];
      bZ  += *(const floatx4*)&ldsC[1][dg][1][col][q*4];
      bNH += *(const floatx4*)&ldsC[1][dg][2][col][q*4];
      bNX += *(const floatx4*)&ldsC[1][dg][3][col][q*4];
      unsigned dwj[4];
      float hnv[4];
      #pragma unroll
      for (int j=0;j<4;++j){
        const float gr = bR[j] + bir;
        const float gz = bZ[j] + biz;
        const float r = __fdividef(1.f, 1.f + __expf(-gr));
        const float z = __fdividef(1.f, 1.f + __expf(-gz));
        float pn = bNX[j] + bin + r*(bNH[j] + bhv);
        pn = fminf(fmaxf(pn, -20.f), 20.f);
        const float e2 = __expf(-2.f*pn);
        const float n  = __fdividef(1.f - e2, 1.f + e2);
        const float hn  = (1.f - z)*n + z*holdB[j];
        const float hnx = (t < LrB[j]) ? hn : holdB[j];
        holdB[j] = hnx;
        hnv[j] = hn;
        unsigned bf = f2bf(hnx);
        unsigned ot = (unsigned)__shfl_xor((int)bf, 1);
        dwj[j] = (l & 1) ? 0u : (bf | (ot << 16));
      }
      if (t < T_SEQ-1){
        if ((l & 1) == 0){
          char* dst = hxB + cur*8192 + ((kg_o*64 + 16*(d5>>3))*16 + (d5&7)*2);
          #pragma unroll
          for (int j=0;j<4;++j)
            st32a(dst + (q*4+j)*16, dwj[j]);
        }
        asm volatile("s_waitcnt vmcnt(0)" ::: "memory");
        __builtin_amdgcn_sched_barrier(0);
        if (l == 0)
          st32a(stgB + wslot, (unsigned)(t+1));
      }
      #pragma unroll
      for (int j=0;j<4;++j){
        const int rj = q*4 + j;
        int tp = d ? (LrB[j]-1-t) : t;
        if (tp < 0) tp += T_SEQ;
        out[((size_t)(b_baseB+rj)*T_SEQ + tp)*512 + d*256 + jd] = hnv[j];
      }
    } else {
      if (t < T_SEQ-1){
        xstoreG(r0, sb0, nxt, 1);
        xstoreG(r0+256, sb1, nxt, 1);
        if (r0 < 16) xstoreG(r0+512, sb2, nxt, 1);
      }
    }
    // no bar3 needed: next iteration's bar1 closes all cross-phase hazards
  }
}

extern "C" void kernel_launch(void* const* d_in, const int* in_sizes, int n_in,
                              void* d_out, int out_size, void* d_ws, size_t ws_size,
                              hipStream_t stream) {
  (void)in_sizes; (void)n_in; (void)out_size; (void)ws_size;
  const float* spike = (const float*)d_in[0];
  const float* extin = (const float*)d_in[1];
  const int*   lens  = (const int*)  d_in[2];
  const float* WiF   = (const float*)d_in[3];
  const float* WhF   = (const float*)d_in[4];
  const float* biF   = (const float*)d_in[5];
  const float* bhF   = (const float*)d_in[6];
  const float* WiB   = (const float*)d_in[7];
  const float* WhB   = (const float*)d_in[8];
  const float* biB   = (const float*)d_in[9];
  const float* bhB   = (const float*)d_in[10];
  float* out = (float*)d_out;
  char* ws = (char*)d_ws;

  // zero stamps + both hx slots of all 32 groups (slot 1 must read h=0 at
  // t=0; also resets state between graph replays)
  hipMemsetAsync(ws, 0, WS_ZERO_BYTES, stream);
  bigru10<<<dim3(NWG), dim3(WGS), 0, stream>>>(
      spike, extin, lens, WiF, WhF, biF, bhF, WiB, WhB, biB, bhB, out, ws);
}